// Round 4
// baseline (234.453 us; speedup 1.0000x reference)
//
#include <hip/hip_runtime.h>
#include <math.h>

// ---- NSA hyperparameters (compile-time, matches reference config) ----
constexpr int kT    = 2048;
constexpr int kHQ   = 16;
constexpr int kD    = 128;
constexpr int kKS   = 32;
constexpr int kST   = 16;
constexpr int kBS   = 64;
constexpr int kM    = (kT - kKS) / kST + 1;   // 127 compressed tokens
constexpr int kNB   = (kT + kBS - 1) / kBS;   // 32 selection blocks
constexpr int kTopN = 16;
constexpr int kNInit = 2;
constexpr int kWIN  = 512;
constexpr float kNEG = -1e30f;
constexpr float kScale = 0.08838834764831845f; // 128^-0.5

constexpr int kPad    = 32;
constexpr int kKBRows = kT + kPad; // 2080
constexpr int kVTCols = kT + kPad; // 2080

// K2 (cmp-attn) LDS strides
constexpr int kQS2 = kD + 4;   // 132 floats
constexpr int kPS2 = 136;      // fp32 probs
constexpr int kPB2 = 136;      // bf16 probs

// K4 attention: P slab row stride (fp16); 16B-aligned rows for b128 reads
constexpr int kPSt  = 72;

typedef __attribute__((ext_vector_type(8))) short short8;
typedef __attribute__((ext_vector_type(8))) _Float16 half8;
typedef __attribute__((ext_vector_type(4))) _Float16 half4v;
typedef __attribute__((ext_vector_type(4))) float floatx4;

// RNE float -> bf16 bits
__device__ inline short f2bf(float x) {
    unsigned u = __float_as_uint(x);
    unsigned r = (u + 0x7fffu + ((u >> 16) & 1u)) >> 16;
    return (short)r;
}

// ---------------------------------------------------------------------
// K1: fused staging.  blocks [0,2080): bf16 K rows + fp16 V^T cols.
// V^T key permutation within each 64-block: col = 4*(w&15) + (w>>4)
// (w = key mod 64), matching K4's swapped-QK P-fragment layout so each
// lane's 4 kt-values store as one contiguous half4.
// NOTE: pad rows (row >= kT) must NOT write vt — the permutation maps
// w in [0,32) to cols up to 61, which would overflow the 32-col pad
// region into the next d-row / past the buffer (R3 bug).  Pad cols are
// never read (K4 touches cols < kT only).
// blocks [2080,2208): mean-pool cmp_k fp32 + cmp V^T bf16.  block=(128)
// ---------------------------------------------------------------------
__global__ void k_stage(const float* __restrict__ k, const float* __restrict__ v,
                        short* __restrict__ kb, _Float16* __restrict__ vt,
                        float* __restrict__ cmp_k, short* __restrict__ cvt) {
    const int bid = blockIdx.x;
    const int d = threadIdx.x;
    if (bid < kKBRows) {
        const int row = bid;
        if (row < kT) {
            const int blk = row >> 6, w = row & 63;
            const int col = blk * kBS + 4 * (w & 15) + (w >> 4);
            kb[row * kD + d] = f2bf(k[(size_t)row * kD + d]);
            vt[(size_t)d * kVTCols + col] = (_Float16)v[(size_t)row * kD + d];
        } else {
            kb[row * kD + d] = 0;   // kb pad rows in-bounds, never read
        }
    } else {
        const int m = bid - kKBRows;        // 0..127 (127 = zero pad row)
        float sk = 0.f, sv = 0.f;
        if (m < kM) {
            const int base = m * kST;
            #pragma unroll
            for (int i = 0; i < kKS; ++i) {
                sk += k[(size_t)(base + i) * kD + d];
                sv += v[(size_t)(base + i) * kD + d];
            }
            sk *= (1.0f / kKS);
            sv *= (1.0f / kKS);
        }
        cmp_k[m * kD + d] = sk;
        cvt[d * 128 + m] = f2bf(sv);
    }
}

// ---------------------------------------------------------------------
// K2: compressed attention + fused top-k, all 16 heads of one t.
// QK fp32 VALU; softmax wave-parallel (16-lane group per head);
// top-k via rank: selected <=> #{b' before b under (val,-idx)} < 16 —
// exact serial-argmax semantics, fully parallel (no shuffle rounds).
// PV: bf16 MFMA.  grid=(T), block=(256)
// ---------------------------------------------------------------------
__global__ __launch_bounds__(256) void k_cmp_attn(
        const float* __restrict__ q, const float* __restrict__ cw,
        const float* __restrict__ cmp_k, const short* __restrict__ cvt,
        unsigned* __restrict__ sel_mask, float* __restrict__ out) {
    const int t = blockIdx.x;
    const int tid = threadIdx.x;
    const int wave = tid >> 6;
    const int lane = tid & 63;
    const int l15 = lane & 15;
    const int quad = lane >> 4;

    __shared__ float q_s[kHQ * kQS2];
    __shared__ float p_s[kHQ * kPS2];
    __shared__ short Pb[kHQ * kPB2];
    __shared__ float sp[kNB];

    // vectorized q staging: 512 float4s, 2 per thread
    for (int i = tid; i < kHQ * kD / 4; i += 256) {
        const int h = i >> 5, d4 = i & 31;
        *(float4*)&q_s[h * kQS2 + d4 * 4] = *(const float4*)&q[(size_t)t * kHQ * kD + i * 4];
    }
    __syncthreads();

    const int nvalid = (t >= kKS - 1) ? min(kM, (t - (kKS - 1)) / kST + 1) : 0;

    for (int idx = tid; idx < nvalid * 4; idx += 256) {
        const int m = idx >> 2;
        const int h0 = (idx & 3) * 4;
        const float4* k4 = (const float4*)(cmp_k + (size_t)m * kD);
        float a0 = 0.f, a1 = 0.f, a2 = 0.f, a3 = 0.f;
        #pragma unroll
        for (int i = 0; i < kD / 4; ++i) {
            const float4 b = k4[i];
            const float4 qa = *(const float4*)&q_s[(h0 + 0) * kQS2 + i * 4];
            const float4 qb = *(const float4*)&q_s[(h0 + 1) * kQS2 + i * 4];
            const float4 qc = *(const float4*)&q_s[(h0 + 2) * kQS2 + i * 4];
            const float4 qd = *(const float4*)&q_s[(h0 + 3) * kQS2 + i * 4];
            a0 = fmaf(qa.x, b.x, fmaf(qa.y, b.y, fmaf(qa.z, b.z, fmaf(qa.w, b.w, a0))));
            a1 = fmaf(qb.x, b.x, fmaf(qb.y, b.y, fmaf(qb.z, b.z, fmaf(qb.w, b.w, a1))));
            a2 = fmaf(qc.x, b.x, fmaf(qc.y, b.y, fmaf(qc.z, b.z, fmaf(qc.w, b.w, a2))));
            a3 = fmaf(qd.x, b.x, fmaf(qd.y, b.y, fmaf(qd.z, b.z, fmaf(qd.w, b.w, a3))));
        }
        p_s[(h0 + 0) * kPS2 + m] = a0 * kScale;
        p_s[(h0 + 1) * kPS2 + m] = a1 * kScale;
        p_s[(h0 + 2) * kPS2 + m] = a2 * kScale;
        p_s[(h0 + 3) * kPS2 + m] = a3 * kScale;
    }
    __syncthreads();

    // ---- wave-parallel softmax: 16-lane group per head, fp32 ----
    {
        const int h = tid >> 4;          // head 0..15
        const int j = tid & 15;
        float* p = p_s + h * kPS2;
        short* pb = Pb + h * kPB2;
        float loc[8];
        float mx = kNEG;
        #pragma unroll
        for (int i = 0; i < 8; ++i) {
            const int m = j + i * 16;
            const float val = (m < nvalid) ? p[m] : kNEG;
            loc[i] = val;
            mx = fmaxf(mx, val);
        }
        #pragma unroll
        for (int off = 8; off; off >>= 1) mx = fmaxf(mx, __shfl_xor(mx, off, 16));
        float e[8];
        float s = 0.f;
        #pragma unroll
        for (int i = 0; i < 8; ++i) {
            const int m = j + i * 16;
            const float ev = (m < nvalid) ? __expf(loc[i] - mx) : 0.f;
            e[i] = ev;
            s += ev;
        }
        #pragma unroll
        for (int off = 8; off; off >>= 1) s += __shfl_xor(s, off, 16);
        const float inv = (nvalid > 0) ? (1.f / s) : 0.f;
        #pragma unroll
        for (int i = 0; i < 8; ++i) {
            const int m = j + i * 16;
            const float pn = e[i] * inv;
            p[m] = pn;                 // zero-fills m >= nvalid too
            pb[m] = f2bf(pn);
        }
    }
    __syncthreads();

    // ---- fused slc_p + rank-based top-k: lanes 0..31 (wave 0) ----
    if (tid < kNB) {
        const int b = tid;
        const int m0 = 4 * b;
        float acc = 0.f;
        for (int h = 0; h < kHQ; ++h) {
            const float* p = p_s + h * kPS2;
            float a = 0.f;
            a += p[m0];
            a += p[m0 + 1];
            a += p[m0 + 2];
            a += 0.5f * p[m0 + 3];
            if (m0 - 1 >= 0) a += 0.5f * p[m0 - 1];
            acc += a;
        }
        const int cur = t / kBS;
        float x = acc;
        if (b > cur) x = kNEG;
        if (b < kNInit || b == cur) x = 1e30f;
        sp[b] = x;                       // in-wave LDS broadcast (no barrier)
        int rank = 0;
        #pragma unroll
        for (int b2 = 0; b2 < kNB; ++b2) {
            const float y = sp[b2];
            rank += (y > x || (y == x && b2 < b)) ? 1 : 0;
        }
        const unsigned long long bm = __ballot(rank < kTopN);
        if (tid == 0) sel_mask[t] = (unsigned)bm;
    }

    // ---- PV: bf16 MFMA (Pb ready since last barrier) ----
    const int dimbase = wave * 32;
    floatx4 o[2] = {{0,0,0,0},{0,0,0,0}};
    #pragma unroll
    for (int kc = 0; kc < 4; ++kc) {
        const short8 ap = *(const short8*)&Pb[l15 * kPB2 + kc * 32 + quad * 8];
        #pragma unroll
        for (int nt = 0; nt < 2; ++nt) {
            const short8 b = *(const short8*)(cvt + (size_t)(dimbase + nt * 16 + l15) * 128 + kc * 32 + quad * 8);
            o[nt] = __builtin_amdgcn_mfma_f32_16x16x32_bf16(ap, b, o[nt], 0, 0, 0);
        }
    }

    #pragma unroll
    for (int r = 0; r < 4; ++r) {
        const int head = quad * 4 + r;
        const float c0 = cw[((size_t)t * kHQ + head) * 3 + 0];
        const float w0 = 1.f / (1.f + __expf(-c0));
        #pragma unroll
        for (int nt = 0; nt < 2; ++nt)
            out[((size_t)t * kHQ + head) * kD + dimbase + nt * 16 + l15] = w0 * o[nt][r];
    }
}

// ---------------------------------------------------------------------
// K4: swapped-QK select+SWA attention.  One WAVE = one query t (block=64,
// grid=T, parity pairing light/heavy).  Swapped QK^T (mfma(K,Q)) makes
// each lane hold 16 keys of ONE head -> softmax reduction is in-register
// + 2 full-wave shuffles (was 64 width-16 shuffles).  P goes through a
// wave-private LDS slab as half4 b64 stores (col = 4*(key&15)+(key>>4),
// matching vt's permutation); PV f16 MFMA.  No barriers anywhere.
// ---------------------------------------------------------------------
__global__ __launch_bounds__(64, 1) void k_attn_tile(
        const float* __restrict__ q, const short* __restrict__ kb,
        const _Float16* __restrict__ vt, const float* __restrict__ cw,
        const unsigned* __restrict__ sel_mask, float* __restrict__ out) {
    const int lane = threadIdx.x;
    const int l15 = lane & 15;
    const int quad = lane >> 4;
    const int bid = blockIdx.x;
    const int hf = bid >> 1;
    const int t_w = (bid & 1) ? (kT - 1 - hf) : hf;   // light/heavy pairing

    __shared__ _Float16 PS[16 * kPSt];   // 2.3 KB, wave-private
    __shared__ _Float16 PW[16 * kPSt];

    // Q B-fragment: q[t_w][head=l15][.] * kScale -> bf16
    short8 aq[4];
    {
        const float* qp = q + ((size_t)t_w * kHQ + l15) * kD + quad * 8;
        #pragma unroll
        for (int c = 0; c < 4; ++c) {
            const float4 f0 = *(const float4*)(qp + c * 32);
            const float4 f1 = *(const float4*)(qp + c * 32 + 4);
            short8 a;
            a[0] = f2bf(f0.x * kScale); a[1] = f2bf(f0.y * kScale);
            a[2] = f2bf(f0.z * kScale); a[3] = f2bf(f0.w * kScale);
            a[4] = f2bf(f1.x * kScale); a[5] = f2bf(f1.y * kScale);
            a[6] = f2bf(f1.z * kScale); a[7] = f2bf(f1.w * kScale);
            aq[c] = a;
        }
    }

    const unsigned selm = sel_mask[t_w];
    const int cur = t_w >> 6;
    const int lob = max(0, (t_w - (kWIN - 1)) >> 6);
    const unsigned lm = 0xFFFFFFFFu >> (31 - cur);
    unsigned act = (selm & lm) | (lm & ~((1u << lob) - 1u));

    // per-lane online state for head l15
    float mS = kNEG, lS = 0.f, mW = kNEG, lW = 0.f;
    floatx4 osel[8], oswa[8];
    #pragma unroll
    for (int n8 = 0; n8 < 8; ++n8) {
        osel[n8] = (floatx4){0,0,0,0};
        oswa[n8] = (floatx4){0,0,0,0};
    }

    while (act) {
        const int b = __builtin_ctz(act);
        act &= act - 1u;
        const bool bsel = (selm >> b) & 1u;
        const bool bswa = b >= lob;

        // ---- K A-frags + V B-frags (L2-resident) ----
        short8 kreg[4][4];
        {
            const short* kp = kb + (size_t)(b * kBS + l15) * kD + quad * 8;
            #pragma unroll
            for (int kt = 0; kt < 4; ++kt)
                #pragma unroll
                for (int c = 0; c < 4; ++c)
                    kreg[kt][c] = *(const short8*)(kp + kt * 16 * kD + c * 32);
        }
        half8 vreg[8][2];
        {
            const _Float16* vp = vt + (size_t)l15 * kVTCols + b * kBS + quad * 8;
            #pragma unroll
            for (int n8 = 0; n8 < 8; ++n8) {
                vreg[n8][0] = *(const half8*)(vp + (size_t)(n8 * 16) * kVTCols);
                vreg[n8][1] = *(const half8*)(vp + (size_t)(n8 * 16) * kVTCols + 32);
            }
        }

        // ---- swapped QK: S[key=b*64+kt*16+quad*4+r][head=l15] ----
        floatx4 acc[4];
        #pragma unroll
        for (int kt = 0; kt < 4; ++kt) {
            acc[kt] = (floatx4){0,0,0,0};
            #pragma unroll
            for (int c = 0; c < 4; ++c)
                acc[kt] = __builtin_amdgcn_mfma_f32_16x16x32_bf16(kreg[kt][c], aq[c], acc[kt], 0, 0, 0);
        }

        const int kbase = b * kBS + quad * 4;

        // ---- block max per path: in-lane tree + 2 wave shuffles ----
        float bmS = kNEG, bmW = kNEG;
        #pragma unroll
        for (int kt = 0; kt < 4; ++kt) {
            #pragma unroll
            for (int r = 0; r < 4; ++r) {
                const int key = kbase + kt * 16 + r;
                const float s = acc[kt][r];
                const bool ca = key <= t_w;
                const bool wi = ca && (t_w - key) < kWIN;
                if (ca) bmS = fmaxf(bmS, s);
                if (wi) bmW = fmaxf(bmW, s);
            }
        }
        bmS = fmaxf(bmS, __shfl_xor(bmS, 16));
        bmS = fmaxf(bmS, __shfl_xor(bmS, 32));
        bmW = fmaxf(bmW, __shfl_xor(bmW, 16));
        bmW = fmaxf(bmW, __shfl_xor(bmW, 32));

        float aS = 1.f, aW = 1.f;
        float mSn = mS, mWn = mW;
        if (bsel) { mSn = fmaxf(mS, bmS); aS = __expf(mS - mSn); }
        if (bswa) { mWn = fmaxf(mW, bmW); aW = __expf(mW - mWn); }

        // ---- exp + P write (half4 per r per path) + partial sums ----
        float sumS = 0.f, sumW = 0.f;
        if (bsel && bswa) {
            const float crv = __expf(mSn - mWn);
            #pragma unroll
            for (int r = 0; r < 4; ++r) {
                half4v hs, hw;
                #pragma unroll
                for (int kt = 0; kt < 4; ++kt) {
                    const int key = kbase + kt * 16 + r;
                    const bool ca = key <= t_w;
                    const bool wi = ca && (t_w - key) < kWIN;
                    const float e0 = ca ? __expf(acc[kt][r] - mSn) : 0.f;
                    const float e1 = wi ? e0 * crv : 0.f;
                    sumS += e0; sumW += e1;
                    hs[kt] = (_Float16)e0;
                    hw[kt] = (_Float16)e1;
                }
                *(half4v*)&PS[l15 * kPSt + 16 * quad + 4 * r] = hs;
                *(half4v*)&PW[l15 * kPSt + 16 * quad + 4 * r] = hw;
            }
        } else if (bsel) {
            #pragma unroll
            for (int r = 0; r < 4; ++r) {
                half4v hs;
                #pragma unroll
                for (int kt = 0; kt < 4; ++kt) {
                    const int key = kbase + kt * 16 + r;
                    const bool ca = key <= t_w;
                    const float e0 = ca ? __expf(acc[kt][r] - mSn) : 0.f;
                    sumS += e0;
                    hs[kt] = (_Float16)e0;
                }
                *(half4v*)&PS[l15 * kPSt + 16 * quad + 4 * r] = hs;
            }
        } else {
            #pragma unroll
            for (int r = 0; r < 4; ++r) {
                half4v hw;
                #pragma unroll
                for (int kt = 0; kt < 4; ++kt) {
                    const int key = kbase + kt * 16 + r;
                    const bool ca = key <= t_w;
                    const bool wi = ca && (t_w - key) < kWIN;
                    const float e1 = wi ? __expf(acc[kt][r] - mWn) : 0.f;
                    sumW += e1;
                    hw[kt] = (_Float16)e1;
                }
                *(half4v*)&PW[l15 * kPSt + 16 * quad + 4 * r] = hw;
            }
        }
        sumS += __shfl_xor(sumS, 16);
        sumS += __shfl_xor(sumS, 32);
        sumW += __shfl_xor(sumW, 16);
        sumW += __shfl_xor(sumW, 32);
        if (bsel) { lS = lS * aS + sumS; mS = mSn; }
        if (bswa) { lW = lW * aW + sumW; mW = mWn; }

        // ---- α broadcast to PV head layout (head = quad*4+r) ----
        float aSh[4], aWh[4];
        #pragma unroll
        for (int r = 0; r < 4; ++r) {
            aSh[r] = __shfl(aS, quad * 4 + r);
            aWh[r] = __shfl(aW, quad * 4 + r);
        }

        // ---- PV: A-frag from wave-private slab, V in registers ----
        half8 apS0, apS1, apW0, apW1;
        if (bsel) {
            apS0 = *(const half8*)&PS[l15 * kPSt + quad * 8];
            apS1 = *(const half8*)&PS[l15 * kPSt + 32 + quad * 8];
        }
        if (bswa) {
            apW0 = *(const half8*)&PW[l15 * kPSt + quad * 8];
            apW1 = *(const half8*)&PW[l15 * kPSt + 32 + quad * 8];
        }

        #pragma unroll
        for (int n8 = 0; n8 < 8; ++n8) {
            if (bsel) {
                #pragma unroll
                for (int r = 0; r < 4; ++r) osel[n8][r] *= aSh[r];
                osel[n8] = __builtin_amdgcn_mfma_f32_16x16x32_f16(apS0, vreg[n8][0], osel[n8], 0, 0, 0);
                osel[n8] = __builtin_amdgcn_mfma_f32_16x16x32_f16(apS1, vreg[n8][1], osel[n8], 0, 0, 0);
            }
            if (bswa) {
                #pragma unroll
                for (int r = 0; r < 4; ++r) oswa[n8][r] *= aWh[r];
                oswa[n8] = __builtin_amdgcn_mfma_f32_16x16x32_f16(apW0, vreg[n8][0], oswa[n8], 0, 0, 0);
                oswa[n8] = __builtin_amdgcn_mfma_f32_16x16x32_f16(apW1, vreg[n8][1], oswa[n8], 0, 0, 0);
            }
        }
    }

    // ---- epilogue: normalizers (shfl to PV head layout) + combine ----
    const float lsI = 1.f / lS;
    const float lwI = 1.f / lW;

    #pragma unroll
    for (int r = 0; r < 4; ++r) {
        const int h = quad * 4 + r;
        const float lsH = __shfl(lsI, h);
        const float lwH = __shfl(lwI, h);
        const float c1 = cw[((size_t)t_w * kHQ + h) * 3 + 1];
        const float c2 = cw[((size_t)t_w * kHQ + h) * 3 + 2];
        const float w1 = 1.f / (1.f + __expf(-c1));
        const float w2 = 1.f / (1.f + __expf(-c2));
        float* op = out + ((size_t)t_w * kHQ + h) * kD + l15;
        #pragma unroll
        for (int n8 = 0; n8 < 8; ++n8)
            op[n8 * 16] += w1 * osel[n8][r] * lsH + w2 * oswa[n8][r] * lwH;
    }
}

// ---------------------------------------------------------------------
extern "C" void kernel_launch(void* const* d_in, const int* in_sizes, int n_in,
                              void* d_out, int out_size, void* d_ws, size_t ws_size,
                              hipStream_t stream) {
    const float* q  = (const float*)d_in[0];
    const float* k  = (const float*)d_in[1];
    const float* v  = (const float*)d_in[2];
    const float* cw = (const float*)d_in[3];
    float* out = (float*)d_out;

    float* ws = (float*)d_ws;
    float* cmp_k = ws;                                   // 128*128 fp32
    unsigned* sel_mask = (unsigned*)(cmp_k + 128 * kD);  // T u32
    short* kb      = (short*)(sel_mask + kT);            // kKBRows*kD bf16
    _Float16* vt   = (_Float16*)(kb + (size_t)kKBRows * kD);  // kD*kVTCols fp16
    short* cvt     = (short*)(vt + (size_t)kD * kVTCols);     // 128*128 bf16

    k_stage<<<dim3(kKBRows + 128), dim3(kD), 0, stream>>>(k, v, kb, vt, cmp_k, cvt);
    k_cmp_attn<<<dim3(kT), dim3(256), 0, stream>>>(q, cw, cmp_k, cvt, sel_mask, out);
    k_attn_tile<<<dim3(kT), dim3(64), 0, stream>>>(q, kb, vt, cw, sel_mask, out);
}